// Round 1
// baseline (2369.955 us; speedup 1.0000x reference)
//
#include <hip/hip_runtime.h>
#include <hip/hip_bf16.h>
#include <cmath>
#include <cstdint>

#define NPT 4095      // nodes per tree
#define NT  32760     // total nodes (8 trees)
#define FD  512       // hidden/feature dim

using bf16 = __hip_bfloat16;
using bf8v = __attribute__((ext_vector_type(8))) short;   // 8 bf16 (4 VGPRs)
using f4v  = __attribute__((ext_vector_type(4))) float;   // MFMA accumulator

__device__ __forceinline__ float b2f(bf16 x){ return __bfloat162float(x); }
__device__ __forceinline__ bf16  f2b(float x){ return __float2bfloat16(x); }
__device__ __forceinline__ float sigf(float x){ return 1.f/(1.f + expf(-x)); }

// ---------------- elementwise / gather kernels ----------------

__global__ void cvt_b16(bf16* __restrict__ dst, const float* __restrict__ src, int n){
  int e = blockIdx.x*256 + threadIdx.x;
  if (e < n) dst[e] = f2b(src[e]);
}

// copy one 512x512 fp32 matrix into packed bf16 dst at (ro,co), row stride dstK
__global__ void pack_w(bf16* __restrict__ dst, int dstK, int ro, int co, const float* __restrict__ src){
  int e = blockIdx.x*256 + threadIdx.x;      // 512*512 elements
  int r = e >> 9, c = e & 511;
  dst[(size_t)(ro + r)*dstK + (co + c)] = f2b(src[e]);
}

// h[leaf] = (1-z)*tanh_c  (z, t stored fp32 by leaf GEMM)
__global__ void leaf_combine(bf16* __restrict__ h_b, const float* __restrict__ zb, const float* __restrict__ tb){
  int e = blockIdx.x*256 + threadIdx.x;      // 16384*512
  int m = e >> 9, n = e & 511;
  int tree = m >> 11, pos = m & 2047;
  size_t node = (size_t)tree*NPT + pos;
  h_b[node*FD + n] = f2b((1.f - zb[e]) * tb[e]);
}

// s_b[m,:] = h[son0] + h[son1] for father m of this level
__global__ void hsum_k(bf16* __restrict__ s_b, const bf16* __restrict__ h_b, int son_start, int l2f){
  int e = blockIdx.x*256 + threadIdx.x;      // Mf*512
  int m = e >> 9, n = e & 511;
  int tree = m >> l2f, pos = m & ((1<<l2f)-1);
  size_t s0 = ((size_t)tree*NPT + son_start + 2*pos)*FD + n;
  s_b[e] = f2b(b2f(h_b[s0]) + b2f(h_b[s0 + FD]));
}

// s_b[m,:] = hd[father(m)] for son m of this level
__global__ void hfa_k(bf16* __restrict__ s_b, const bf16* __restrict__ hd_b, int fa_start, int l2s){
  int e = blockIdx.x*256 + threadIdx.x;      // Ms*512
  int m = e >> 9, n = e & 511;
  int tree = m >> l2s, pos = m & ((1<<l2s)-1);
  size_t f = ((size_t)tree*NPT + fa_start + (pos >> 1))*FD + n;
  s_b[e] = hd_b[f];
}

// rh = bf16(r * s)
__global__ void rh_k(bf16* __restrict__ rh, const float* __restrict__ r, const bf16* __restrict__ s){
  int e = blockIdx.x*256 + threadIdx.x;
  rh[e] = f2b(r[e] * b2f(s[e]));
}

// hd[root] = h[root]
__global__ void roots_k(bf16* __restrict__ hd, const bf16* __restrict__ h){
  int e = blockIdx.x*256 + threadIdx.x;      // 8*512
  int t = e >> 9, n = e & 511;
  size_t node = (size_t)t*NPT + 4094;
  hd[node*FD + n] = h[node*FD + n];
}

// ---------------- the workhorse GEMM ----------------
// Y[m,n] = sum_k Ain[m,k] * Wp[n,k],  K in {512,1024}, N = gridDim.y*64
// Ain row m: k<512 -> A0[node(m)*512 + k]  (node = tree*NPT + a_start + pos)
//            k>=512 -> A1[m*512 + (k-512)]
// modes: 0 leaf (n<512: sig->outA fp32 ; n>=512: tanh->outB fp32)
//        1 gates (n<512: sig(v+bias0[n])->outA ; else sig(v+bias1[n-512])->outB)
//        2 combine (N=512): c=tanh(v); h=z*s+(1-z)*c; outH[onode(m)*512+n]=bf16(h)
//        4 out (N=512): outF[m*512+n] = v + bias0[n] + bias1[n]
__global__ __launch_bounds__(256) void gemm_k(
    const bf16* __restrict__ A0, const bf16* __restrict__ A1,
    const bf16* __restrict__ Wp, int M, int K,
    int a_start, int a_log2, int o_start, int o_log2,
    const float* __restrict__ bias0, const float* __restrict__ bias1,
    const float* __restrict__ zbuf, const bf16* __restrict__ sbuf,
    float* __restrict__ outA, float* __restrict__ outB,
    bf16* __restrict__ outH, float* __restrict__ outF, int mode)
{
  const int lane = threadIdx.x & 63;
  const int wid  = threadIdx.x >> 6;
  const int wr = wid >> 1, wc = wid & 1;
  const int m_base = blockIdx.x*64 + wr*32;
  const int n_base = blockIdx.y*64 + wc*32;
  const int lr   = lane & 15;
  const int quad = lane >> 4;

  f4v acc[2][2] = {};

  // per-lane A row precompute (lane lr indexes the 16 rows of each m-tile)
  int am[2]; long arow[2]; bool av[2];
  const int amask = (1 << a_log2) - 1;
  #pragma unroll
  for (int mt = 0; mt < 2; ++mt){
    int m = m_base + mt*16 + lr;
    av[mt] = (m < M);
    int mm = av[mt] ? m : 0;
    am[mt] = mm;
    int tree = mm >> a_log2, pos = mm & amask;
    arow[mt] = (long)tree*NPT + a_start + pos;
  }

  for (int k0 = 0; k0 < K; k0 += 32){
    int k = k0 + quad*8;
    bf8v a[2], b[2];
    #pragma unroll
    for (int mt = 0; mt < 2; ++mt){
      const bf16* p = (k0 < 512) ? (A0 + arow[mt]*FD + k)
                                 : (A1 + (long)am[mt]*FD + (k - 512));
      bf8v t = {};
      if (av[mt]) t = *(const bf8v*)p;
      a[mt] = t;
    }
    #pragma unroll
    for (int nt = 0; nt < 2; ++nt){
      int n = n_base + nt*16 + lr;
      b[nt] = *(const bf8v*)(Wp + (long)n*K + k);
    }
    #pragma unroll
    for (int mt = 0; mt < 2; ++mt)
      #pragma unroll
      for (int nt = 0; nt < 2; ++nt)
        acc[mt][nt] = __builtin_amdgcn_mfma_f32_16x16x32_bf16(a[mt], b[nt], acc[mt][nt], 0, 0, 0);
  }

  const int omask = (1 << o_log2) - 1;
  #pragma unroll
  for (int mt = 0; mt < 2; ++mt){
    int rbase = m_base + mt*16 + quad*4;   // C/D: row=(lane>>4)*4+i, col=lane&15
    #pragma unroll
    for (int nt = 0; nt < 2; ++nt){
      int n = n_base + nt*16 + lr;
      #pragma unroll
      for (int i = 0; i < 4; ++i){
        int row = rbase + i;
        if (row >= M) continue;
        float v = acc[mt][nt][i];
        if (mode == 0){
          if (n < 512) outA[(size_t)row*FD + n] = sigf(v);
          else         outB[(size_t)row*FD + (n-512)] = tanhf(v);
        } else if (mode == 1){
          if (n < 512) outA[(size_t)row*FD + n] = sigf(v + bias0[n]);
          else         outB[(size_t)row*FD + (n-512)] = sigf(v + bias1[n-512]);
        } else if (mode == 2){
          float c = tanhf(v);
          float z = zbuf[(size_t)row*FD + n];
          float s = b2f(sbuf[(size_t)row*FD + n]);
          float h = z*s + (1.f - z)*c;
          int tree = row >> o_log2, pos = row & omask;
          long node = (long)tree*NPT + o_start + pos;
          outH[node*FD + n] = f2b(h);
        } else { // mode 4
          outF[(size_t)row*FD + n] = v + bias0[n] + bias1[n];
        }
      }
    }
  }
}

// ---------------- host launcher ----------------

extern "C" void kernel_launch(void* const* d_in, const int* in_sizes, int n_in,
                              void* d_out, int out_size, void* d_ws, size_t ws_size,
                              hipStream_t stream)
{
  const float* feat = (const float*)d_in[0];
  const float* Wh   = (const float*)d_in[1];
  const float* Wz   = (const float*)d_in[2];
  const float* Wr   = (const float*)d_in[3];
  const float* Uh   = (const float*)d_in[4];
  const float* Uz   = (const float*)d_in[5];
  const float* bUz  = (const float*)d_in[6];
  const float* Ur   = (const float*)d_in[7];
  const float* bUr  = (const float*)d_in[8];
  const float* Whd  = (const float*)d_in[9];
  const float* Wzd  = (const float*)d_in[10];
  const float* Wrd  = (const float*)d_in[11];
  const float* Uhd  = (const float*)d_in[12];
  const float* Uzd  = (const float*)d_in[13];
  const float* bUzd = (const float*)d_in[14];
  const float* Urd  = (const float*)d_in[15];
  const float* bUrd = (const float*)d_in[16];
  const float* W1   = (const float*)d_in[17];
  const float* b1   = (const float*)d_in[18];
  const float* W2   = (const float*)d_in[19];
  const float* b2   = (const float*)d_in[20];
  float* out = (float*)d_out;

  // level bookkeeping: starts/sizes per level (per tree)
  int starts[12], szs[12];
  { int s = 0, sz = 2048; for (int l = 0; l < 12; ++l){ starts[l] = s; szs[l] = sz; s += sz; sz >>= 1; } }

  // workspace carve (256B aligned)
  char* p = (char*)d_ws;
  auto take = [&](size_t b)->char*{ char* q = p; p += (b + 255) & ~(size_t)255; return q; };
  bf16* featb = (bf16*)take((size_t)NT*FD*2);
  bf16* h_b   = (bf16*)take((size_t)NT*FD*2);
  bf16* hd_b  = (bf16*)take((size_t)NT*FD*2);
  bf16* Wl    = (bf16*)take((size_t)1024*512*2);   // [Wz ; Wh], K=512
  bf16* Wzr_u = (bf16*)take((size_t)1024*1024*2);  // [[Wz|Uz];[Wr|Ur]], K=1024
  bf16* Whu   = (bf16*)take((size_t)512*1024*2);   // [Wh|Uh], K=1024
  bf16* Wzr_d = (bf16*)take((size_t)1024*1024*2);
  bf16* Whu_d = (bf16*)take((size_t)512*1024*2);
  bf16* Wout  = (bf16*)take((size_t)512*1024*2);   // [W1|W2], K=1024
  float* z_b  = (float*)take((size_t)16384*512*4);
  float* r_b  = (float*)take((size_t)16384*512*4);
  bf16* s_b   = (bf16*)take((size_t)16384*512*2);  // hsum / hfa
  bf16* rh_b  = (bf16*)take((size_t)16384*512*2);
  if ((size_t)(p - (char*)d_ws) > ws_size) return;  // insufficient workspace -> fail visibly

  // --- stage inputs ---
  cvt_b16<<<65520, 256, 0, stream>>>(featb, feat, NT*FD);
  auto pk = [&](bf16* dst, int dk, int ro, int co, const float* src){
    pack_w<<<1024, 256, 0, stream>>>(dst, dk, ro, co, src);
  };
  pk(Wl,   512,   0,   0, Wz);  pk(Wl,   512, 512,   0, Wh);
  pk(Wzr_u,1024,  0,   0, Wz);  pk(Wzr_u,1024,  0, 512, Uz);
  pk(Wzr_u,1024,512,   0, Wr);  pk(Wzr_u,1024,512, 512, Ur);
  pk(Whu,  1024,  0,   0, Wh);  pk(Whu,  1024,  0, 512, Uh);
  pk(Wzr_d,1024,  0,   0, Wzd); pk(Wzr_d,1024,  0, 512, Uzd);
  pk(Wzr_d,1024,512,   0, Wrd); pk(Wzr_d,1024,512, 512, Urd);
  pk(Whu_d,1024,  0,   0, Whd); pk(Whu_d,1024,  0, 512, Uhd);
  pk(Wout, 1024,  0,   0, W1);  pk(Wout, 1024,  0, 512, W2);

  auto gemm = [&](const bf16* A0, const bf16* A1, const bf16* Wp, int M, int N, int K,
                  int a_start, int a_log2, int o_start, int o_log2,
                  const float* bias0, const float* bias1,
                  const float* zbuf, const bf16* sbuf,
                  float* outA, float* outB, bf16* outH, float* outF, int mode){
    dim3 g((M + 63)/64, N/64);
    gemm_k<<<g, 256, 0, stream>>>(A0, A1, Wp, M, K, a_start, a_log2, o_start, o_log2,
                                  bias0, bias1, zbuf, sbuf, outA, outB, outH, outF, mode);
  };

  // --- leaves: z=sig(xWz), t=tanh(xWh); h = (1-z)*t ---
  gemm(featb, nullptr, Wl, 16384, 1024, 512, /*a*/0, 11, 0, 0,
       nullptr, nullptr, nullptr, nullptr, z_b, r_b, nullptr, nullptr, 0);
  leaf_combine<<<32768, 256, 0, stream>>>(h_b, z_b, r_b);

  // --- bottom-up ---
  for (int l = 0; l < 11; ++l){
    int Mf = 8*szs[l+1];
    int l2f = 10 - l;                       // log2(fathers per tree)
    hsum_k<<<Mf*2, 256, 0, stream>>>(s_b, h_b, starts[l], l2f);
    gemm(featb, s_b, Wzr_u, Mf, 1024, 1024, starts[l+1], l2f, 0, 0,
         bUz, bUr, nullptr, nullptr, z_b, r_b, nullptr, nullptr, 1);
    rh_k<<<Mf*2, 256, 0, stream>>>(rh_b, r_b, s_b);
    gemm(featb, rh_b, Whu, Mf, 512, 1024, starts[l+1], l2f, starts[l+1], l2f,
         nullptr, nullptr, z_b, s_b, nullptr, nullptr, h_b, nullptr, 2);
  }

  // --- roots: hd = h ---
  roots_k<<<16, 256, 0, stream>>>(hd_b, h_b);

  // --- top-down ---
  for (int l = 10; l >= 0; --l){
    int Ms = 8*szs[l];
    int l2s = 11 - l;                       // log2(sons per tree)
    hfa_k<<<Ms*2, 256, 0, stream>>>(s_b, hd_b, starts[l+1], l2s);
    gemm(featb, s_b, Wzr_d, Ms, 1024, 1024, starts[l], l2s, 0, 0,
         bUzd, bUrd, nullptr, nullptr, z_b, r_b, nullptr, nullptr, 1);
    rh_k<<<Ms*2, 256, 0, stream>>>(rh_b, r_b, s_b);
    gemm(featb, rh_b, Whu_d, Ms, 512, 1024, starts[l], l2s, starts[l], l2s,
         nullptr, nullptr, z_b, s_b, nullptr, nullptr, hd_b, nullptr, 2);
  }

  // --- output: [h|hd] @ [W1|W2].T + b1 + b2 ---
  gemm(h_b, hd_b, Wout, NT, 512, 1024, 0, 26, 0, 26,
       b1, b2, nullptr, nullptr, nullptr, nullptr, nullptr, out, 4);
}